// Round 5
// baseline (398.038 us; speedup 1.0000x reference)
//
#include <hip/hip_runtime.h>
#include <cstdint>
#include <cstddef>

#define B_ 8
#define N_ 2048
#define H_ 8
#define D_ 32
#define U_ 256

typedef _Float16 half8 __attribute__((ext_vector_type(8)));
typedef _Float16 half4 __attribute__((ext_vector_type(4)));
typedef float float4v __attribute__((ext_vector_type(4)));

__device__ __forceinline__ float fast_exp2(float x) {
#if __has_builtin(__builtin_amdgcn_exp2f)
  return __builtin_amdgcn_exp2f(x);
#else
  return exp2f(x);
#endif
}

// ---------------------------------------------------------------------------
// K0: prep.
//  blocks [0,64):        W transpose -> WT fp16 [n][k], one 64x64 subtile per
//                        block (parallel, was a serial 16-iter loop).
//                        Wq scaled by log2(e)/sqrt(32).
//  blocks [64,64+nx):    X fp32 -> fp16 (nx=512 on full path, 0 on fallback).
//  blocks [64+nx, +1024): Adj -> bitmask Mask[b][ktile][n] (4 MB). Streams the
//                        134 MB Adj ONCE at HBM BW; removes it from k_attn's
//                        latency-bound pipeline.
// ---------------------------------------------------------------------------
__global__ __launch_bounds__(256)
void k_prep(const float* __restrict__ X,
            const float* __restrict__ Wq, const float* __restrict__ Wk,
            const float* __restrict__ Wv, const float* __restrict__ Wo,
            const int* __restrict__ Adj,
            _Float16* __restrict__ Xh, _Float16* __restrict__ WT,
            unsigned* __restrict__ Maskg, int nx)
{
  __shared__ __attribute__((aligned(16))) float Ts[64][68];
  const int tid = threadIdx.x;
  const int bx = blockIdx.x;
  if (bx < 64) {
    const int wsel = bx >> 4;     // which W
    const int t    = bx & 15;     // which 64x64 subtile
    const float* W = (wsel == 0) ? Wq : (wsel == 1) ? Wk : (wsel == 2) ? Wv : Wo;
    const float scale = (wsel == 0) ? 0.25505413f : 1.0f;
    _Float16* dstW = WT + (size_t)wsel * (U_ * U_);
    const int r = tid >> 2, cs = tid & 3;
    const int k0 = (t >> 2) * 64, n0 = (t & 3) * 64;
#pragma unroll
    for (int j = 0; j < 4; ++j)
      *(float4v*)&Ts[r][cs * 16 + j * 4] =
          *(const float4v*)(W + (size_t)(k0 + r) * U_ + n0 + cs * 16 + j * 4);
    __syncthreads();
#pragma unroll
    for (int j = 0; j < 4; ++j) {
      half4 hv;
#pragma unroll
      for (int jj = 0; jj < 4; ++jj)
        hv[jj] = (_Float16)(Ts[cs * 16 + j * 4 + jj][r] * scale);
      *(half4*)(dstW + (size_t)(n0 + r) * U_ + k0 + cs * 16 + j * 4) = hv;
    }
  } else if (bx < 64 + nx) {
    const size_t base = ((size_t)(bx - 64) * 256 + tid) * 32;
#pragma unroll
    for (int i = 0; i < 4; ++i) {
      float4v a  = *(const float4v*)(X + base + i * 8);
      float4v b2 = *(const float4v*)(X + base + i * 8 + 4);
      half8 hv;
      hv[0] = (_Float16)a[0];  hv[1] = (_Float16)a[1];
      hv[2] = (_Float16)a[2];  hv[3] = (_Float16)a[3];
      hv[4] = (_Float16)b2[0]; hv[5] = (_Float16)b2[1];
      hv[6] = (_Float16)b2[2]; hv[7] = (_Float16)b2[3];
      *(half8*)(Xh + base + i * 8) = hv;
    }
  } else {
    // Adj -> Mask. 1024 blocks x 16 rows. Wave covers 2 rows per ballot.
    const int blk  = bx - 64 - nx;          // 0..1023
    const int wv   = tid >> 6;              // 0..3
    const int lane = tid & 63;
    const int rsel = lane >> 5;             // 0/1: which row of the pair
    const int kk   = lane & 31;             // key within 32-word
#pragma unroll
    for (int rp = 0; rp < 4; rp += 2) {
      const int R = blk * 16 + wv * 4 + rp + rsel;   // flat row in [0, B*N)
      const int b = R >> 11;
      const int n = R & (N_ - 1);
      const int* ap = Adj + (size_t)R * N_ + kk;
      unsigned* mp = Maskg + (size_t)b * 64 * N_ + n;
#pragma unroll 4
      for (int t = 0; t < 64; ++t) {
        int av = ap[(size_t)t * 32];
        unsigned long long bm = __ballot(av > 0);
        if (kk == 0) mp[(size_t)t * N_] = (unsigned)(rsel ? (bm >> 32) : bm);
      }
    }
  }
}

// ---------------------------------------------------------------------------
// K1: QKV projection from pre-converted Xh (fp16) and pre-transposed WT.
// 64-row tiles: grid (6,256), LDS 27.6 KB.
// ---------------------------------------------------------------------------
__global__ __launch_bounds__(256, 2)
void k_qkv2(const _Float16* __restrict__ Xh,
            const _Float16* __restrict__ WTq, const _Float16* __restrict__ WTk,
            const _Float16* __restrict__ WTv,
            _Float16* __restrict__ Qg, _Float16* __restrict__ Kg,
            _Float16* __restrict__ VTg)
{
  __shared__ __attribute__((aligned(16))) char qsmem[27648];
  _Float16* Xs = (_Float16*)qsmem;            // [64 m][72]
  _Float16* Ws = (_Float16*)(qsmem + 9216);   // [128 n][72]

  const int tid  = threadIdx.x;
  const int lane = tid & 63;
  const int w    = tid >> 6;
  const int c    = lane & 15;
  const int qd   = lane >> 4;

  const int bx   = blockIdx.x;    // 0..5
  const int proj = bx >> 1;
  const int nh   = bx & 1;
  const int n0l  = nh * 128;
  const int m0   = blockIdx.y * 64;
  const _Float16* WT = (proj == 0) ? WTq : ((proj == 1) ? WTk : WTv);

  const float4v zero4 = {0.f, 0.f, 0.f, 0.f};
  float4v acc[8];
#pragma unroll
  for (int j = 0; j < 8; ++j) acc[j] = zero4;

  const int xrow = tid >> 2, xoff = (tid & 3) * 16;
  const int wrow = tid >> 1, woff = (tid & 1) * 32;
  for (int kt = 0; kt < 4; ++kt) {
    const int k0 = kt * 64;
    {
      const _Float16* src = Xh + (size_t)(m0 + xrow) * U_ + k0 + xoff;
      _Float16* dst = &Xs[xrow * 72 + xoff];
      *(half8*)(dst)     = *(const half8*)(src);
      *(half8*)(dst + 8) = *(const half8*)(src + 8);
    }
    {
      const _Float16* srcw = WT + (size_t)(n0l + wrow) * U_ + k0 + woff;
      _Float16* dstw = &Ws[wrow * 72 + woff];
#pragma unroll
      for (int i = 0; i < 4; ++i)
        *(half8*)(dstw + i * 8) = *(const half8*)(srcw + i * 8);
    }
    __syncthreads();
#pragma unroll
    for (int ks = 0; ks < 2; ++ks) {
      half8 af = *(const half8*)&Xs[(w * 16 + c) * 72 + ks * 32 + qd * 8];
      half8 bf[8];
#pragma unroll
      for (int nt = 0; nt < 8; ++nt)
        bf[nt] = *(const half8*)&Ws[(nt * 16 + c) * 72 + ks * 32 + qd * 8];
#pragma unroll
      for (int nt = 0; nt < 8; ++nt)
        acc[nt] = __builtin_amdgcn_mfma_f32_16x16x32_f16(af, bf[nt], acc[nt], 0, 0, 0);
    }
    __syncthreads();
  }

  const int b   = m0 >> 11;
  const int nb0 = m0 & (N_ - 1);
  if (proj < 2) {
    _Float16* Og = (proj == 0) ? Qg : Kg;
#pragma unroll
    for (int nt = 0; nt < 8; ++nt)
#pragma unroll
      for (int r = 0; r < 4; ++r) {
        const int rowl = w * 16 + qd * 4 + r;
        Og[(size_t)(b * N_ + nb0 + rowl) * U_ + n0l + nt * 16 + c] = (_Float16)acc[nt][r];
      }
  } else {
    _Float16* tr = (_Float16*)qsmem; // [128 u][72 seq]
#pragma unroll
    for (int nt = 0; nt < 8; ++nt)
#pragma unroll
      for (int r = 0; r < 4; ++r)
        tr[(nt * 16 + c) * 72 + w * 16 + qd * 4 + r] = (_Float16)acc[nt][r];
    __syncthreads();
    const int u = tid >> 1;
    const int seg = tid & 1;
    _Float16* dst = VTg + (size_t)(b * U_ + n0l + u) * N_ + nb0 + seg * 32;
#pragma unroll
    for (int i = 0; i < 4; ++i)
      *(half8*)(dst + i * 8) = *(const half8*)&tr[u * 72 + seg * 32 + i * 8];
  }
}

// ---------------------------------------------------------------------------
// K1 (fallback, ws too small): original QKV with in-kernel transpose.
// ---------------------------------------------------------------------------
__global__ __launch_bounds__(256, 2)
void k_qkv(const float* __restrict__ X,
           const float* __restrict__ Wq, const float* __restrict__ Wk,
           const float* __restrict__ Wv,
           _Float16* __restrict__ Qg, _Float16* __restrict__ Kg,
           _Float16* __restrict__ VTg)
{
  __shared__ __attribute__((aligned(16))) char qsmem[36864];
  _Float16* Xs = (_Float16*)qsmem;
  _Float16* Ws = (_Float16*)(qsmem + 18432);

  const int tid  = threadIdx.x;
  const int lane = tid & 63;
  const int w    = tid >> 6;
  const int c    = lane & 15;
  const int qd   = lane >> 4;

  const int bx   = blockIdx.x;
  const int proj = bx >> 1;
  const int nh   = bx & 1;
  const int n0l  = nh * 128;
  const int m0   = blockIdx.y * 128;
  const float* Wp = (proj == 0) ? Wq : ((proj == 1) ? Wk : Wv);
  const float wscale = (proj == 0) ? 0.25505413f : 1.0f;

  const float4v zero4 = {0.f, 0.f, 0.f, 0.f};
  float4v acc[2][8];
#pragma unroll
  for (int i = 0; i < 2; ++i)
#pragma unroll
    for (int j = 0; j < 8; ++j) acc[i][j] = zero4;

  for (int kt = 0; kt < 4; ++kt) {
    const int k0 = kt * 64;
    {
      const int row = tid >> 1;
      const int off = (tid & 1) * 32;
      const float* src = X + (size_t)(m0 + row) * U_ + k0 + off;
      _Float16* dst = &Xs[row * 72 + off];
#pragma unroll
      for (int i = 0; i < 4; ++i) {
        float4v a  = *(const float4v*)(src + i * 8);
        float4v b2 = *(const float4v*)(src + i * 8 + 4);
        half8 hv;
        hv[0] = (_Float16)a[0];  hv[1] = (_Float16)a[1];
        hv[2] = (_Float16)a[2];  hv[3] = (_Float16)a[3];
        hv[4] = (_Float16)b2[0]; hv[5] = (_Float16)b2[1];
        hv[6] = (_Float16)b2[2]; hv[7] = (_Float16)b2[3];
        *(half8*)(dst + i * 8) = hv;
      }
    }
    {
      const int kl = tid & 63;
      const int ng = tid >> 6;
      const float* srcw = Wp + (size_t)(k0 + kl) * U_ + n0l + ng * 32;
#pragma unroll
      for (int j = 0; j < 8; ++j) {
        float4v a = *(const float4v*)(srcw + j * 4);
#pragma unroll
        for (int jj = 0; jj < 4; ++jj)
          Ws[(ng * 32 + j * 4 + jj) * 72 + kl] = (_Float16)(a[jj] * wscale);
      }
    }
    __syncthreads();
#pragma unroll
    for (int ks = 0; ks < 2; ++ks) {
      half8 af[2], bf[8];
#pragma unroll
      for (int mt = 0; mt < 2; ++mt)
        af[mt] = *(const half8*)&Xs[(w * 32 + mt * 16 + c) * 72 + ks * 32 + qd * 8];
#pragma unroll
      for (int nt = 0; nt < 8; ++nt)
        bf[nt] = *(const half8*)&Ws[(nt * 16 + c) * 72 + ks * 32 + qd * 8];
#pragma unroll
      for (int mt = 0; mt < 2; ++mt)
#pragma unroll
        for (int nt = 0; nt < 8; ++nt)
          acc[mt][nt] = __builtin_amdgcn_mfma_f32_16x16x32_f16(af[mt], bf[nt], acc[mt][nt], 0, 0, 0);
    }
    __syncthreads();
  }

  const int b   = m0 >> 11;
  const int nb0 = m0 & (N_ - 1);
  if (proj < 2) {
    _Float16* Og = (proj == 0) ? Qg : Kg;
#pragma unroll
    for (int mt = 0; mt < 2; ++mt)
#pragma unroll
      for (int nt = 0; nt < 8; ++nt)
#pragma unroll
        for (int r = 0; r < 4; ++r) {
          const int rowl = w * 32 + mt * 16 + qd * 4 + r;
          Og[(size_t)(b * N_ + nb0 + rowl) * U_ + n0l + nt * 16 + c] = (_Float16)acc[mt][nt][r];
        }
  } else {
    _Float16* tr = (_Float16*)qsmem;
#pragma unroll
    for (int mt = 0; mt < 2; ++mt)
#pragma unroll
      for (int nt = 0; nt < 8; ++nt)
#pragma unroll
        for (int r = 0; r < 4; ++r)
          tr[(nt * 16 + c) * 136 + w * 32 + mt * 16 + qd * 4 + r] = (_Float16)acc[mt][nt][r];
    __syncthreads();
    const int u = tid >> 1;
    const int seg = tid & 1;
    _Float16* dst = VTg + (size_t)(b * U_ + n0l + u) * N_ + nb0 + seg * 64;
#pragma unroll
    for (int i = 0; i < 8; ++i)
      *(half8*)(dst + i * 8) = *(const half8*)&tr[u * 136 + seg * 64 + i * 8];
  }
}

// ---------------------------------------------------------------------------
// K2: fused masked flash attention + output projection.
// Round 5 structure:
//  * 512 blocks x 1024 threads (16 waves = 8 heads x 2 q-frags), 32 q-rows.
//  * K and V staged via fully-coalesced loads -> XOR-swizzled LDS tiles,
//    NO padding: LDS = 2x16KB (K) + 2x16KB (V) = 65,536 B exactly.
//    All LDS reads <=2-way bank aliasing (free, m136).
//  * Masks precomputed (k_prep): 1 dword/lane/tile from 4 MB L2-resident
//    array, prefetched 2 tiles ahead in regs. No Adj, no ballots here.
//  * Same proven pipeline: loads 2 tiles ahead, 1 barrier/tile.
//  * Epilogue: l-reduce, ctx->LDS (reuse K region), fused Out = ctx@Wo + bo.
// ---------------------------------------------------------------------------
#define KS_HW (32 * 256)    // halves per K buffer (no pad, XOR swizzle)
#define VS_HW (256 * 32)    // halves per V^T buffer (no pad, XOR swizzle)

struct StageRegs {
  half8 k, v;
  unsigned m;
};

__global__ __launch_bounds__(1024, 4)
void k_attn(const _Float16* __restrict__ Qg, const _Float16* __restrict__ Kg,
            const _Float16* __restrict__ VTg, const unsigned* __restrict__ Maskg,
            const _Float16* __restrict__ WTo, const float* __restrict__ bo,
            float* __restrict__ Out)
{
  __shared__ __attribute__((aligned(16))) _Float16 KsB[2][KS_HW];
  __shared__ __attribute__((aligned(16))) _Float16 VsB[2][VS_HW];

  const int tid  = threadIdx.x;
  const int lane = tid & 63;
  const int w    = tid >> 6;   // 0..15
  const int h    = w & 7;      // head
  const int qs   = w >> 3;     // q-frag (0/1), 16 rows each
  const int c    = lane & 15;
  const int qd   = lane >> 4;
  const int wg   = blockIdx.x;
  const int b    = wg & 7;     // XCD-L2 locality
  const int q0   = (wg >> 3) * 32;

  // staging thread roles
  const int krow = tid >> 5, kch = tid & 31;          // K: 32 rows x 32 chunks(16B)
  const int vu   = tid >> 2, vseg = tid & 3;          // V: 256 rows x 4 chunks(16B)
  const _Float16* kptr = Kg + (size_t)(b * N_ + krow) * U_ + kch * 8;
  const _Float16* vptr = VTg + (size_t)(b * U_ + vu) * N_ + vseg * 8;
  const unsigned* mptr = Maskg + (size_t)b * 64 * N_ + q0 + qs * 16 + c;
  // swizzled LDS destinations (halves)
  const int kdst = krow * 256 + ((kch ^ (krow & 7)) << 3);
  const int vdst = vu * 32 + (((vseg << 1) ^ (((vu >> 1) & 3) << 1)) << 2);

  // Q as B-operand frag (pre-scaled by log2(e)/sqrt(d))
  const half8 qb = *(const half8*)(Qg + (size_t)(b * N_ + q0 + qs * 16 + c) * U_ + h * D_ + qd * 8);

  const float4v init4 = {-8.f, -8.f, -8.f, -8.f}; // exp2 bias, cancels in p/l
  const float4v zero4 = {0.f, 0.f, 0.f, 0.f};
  float4v acc[2] = {zero4, zero4};
  float lrow = 0.f;

  // swizzled LDS read offsets (halves)
  const int kaoff = ((h * 4 + qd) ^ (c & 7)) * 8;     // within a K row
  const int vxor  = ((c >> 1) & 3) << 1;              // V granule XOR key

  auto load_tile = [&](int kt) -> StageRegs {
    StageRegs r;
    r.k = *(const half8*)(kptr + (size_t)kt * 32 * U_);
    r.v = *(const half8*)(vptr + (size_t)kt * 32);
    r.m = mptr[(size_t)kt * N_];
    return r;
  };
  auto store_tile = [&](const StageRegs& r, int buf) {
    *(half8*)&KsB[buf][kdst] = r.k;
    *(half8*)&VsB[buf][vdst] = r.v;
  };
  auto compute_tile = [&](int buf, unsigned mw) {
    half8 ka0 = *(const half8*)&KsB[buf][(c) * 256 + kaoff];
    half8 ka1 = *(const half8*)&KsB[buf][(16 + c) * 256 + kaoff];
    half4 va[2][2];
#pragma unroll
    for (int mt = 0; mt < 2; ++mt)
#pragma unroll
      for (int kc = 0; kc < 2; ++kc)
        va[mt][kc] = *(const half4*)&VsB[buf][(h * D_ + mt * 16 + c) * 32 + (((kc << 2) + qd) ^ vxor) * 4];
    float4v s0 = __builtin_amdgcn_mfma_f32_16x16x32_f16(ka0, qb, init4, 0, 0, 0);
    float4v s1 = __builtin_amdgcn_mfma_f32_16x16x32_f16(ka1, qb, init4, 0, 0, 0);
    const unsigned t0 = mw >> (qd * 4);
    const unsigned t1 = mw >> (16 + qd * 4);
    half4 pb0, pb1;
    float ls = 0.f;
#pragma unroll
    for (int r = 0; r < 4; ++r) {
      float e0 = fast_exp2(s0[r]);
      float e1 = fast_exp2(s1[r]);
      float p0 = ((t0 >> r) & 1u) ? e0 : 0.f;
      float p1 = ((t1 >> r) & 1u) ? e1 : 0.f;
      ls += p0 + p1;
      pb0[r] = (_Float16)p0;
      pb1[r] = (_Float16)p1;
    }
    lrow += ls;
    acc[0] = __builtin_amdgcn_mfma_f32_16x16x16f16(va[0][0], pb0, acc[0], 0, 0, 0);
    acc[0] = __builtin_amdgcn_mfma_f32_16x16x16f16(va[0][1], pb1, acc[0], 0, 0, 0);
    acc[1] = __builtin_amdgcn_mfma_f32_16x16x16f16(va[1][0], pb0, acc[1], 0, 0, 0);
    acc[1] = __builtin_amdgcn_mfma_f32_16x16x16f16(va[1][1], pb1, acc[1], 0, 0, 0);
  };

  // ---- prologue ----
  StageRegs rA = load_tile(0);
  store_tile(rA, 0);
  StageRegs rB = load_tile(1);
  __syncthreads();

  // ---- pipelined main loop: loads run 2 tiles ahead of consumption ----
#pragma unroll 1
  for (int kt = 0; kt < 64; kt += 2) {
    const unsigned m0 = rA.m;
    if (kt + 2 < 64) rA = load_tile(kt + 2);
    compute_tile(0, m0);                 // tile kt
    store_tile(rB, 1);                   // tile kt+1
    __syncthreads();
    const unsigned m1 = rB.m;
    if (kt + 3 < 64) rB = load_tile(kt + 3);
    compute_tile(1, m1);                 // tile kt+1
    if (kt + 2 < 64) store_tile(rA, 0);  // tile kt+2
    __syncthreads();
  }

  // ---- epilogue 1: reduce l across qd-groups, normalize, ctx -> LDS ----
  float l = lrow;
  l += __shfl_xor(l, 16, 64);
  l += __shfl_xor(l, 32, 64);
  const float rinv = (l > 0.f) ? 1.f / l : 0.f;

  _Float16* ctxS = (_Float16*)KsB;  // reuse K region: [32 q][264]
#pragma unroll
  for (int mt = 0; mt < 2; ++mt) {
    half4 hv;
#pragma unroll
    for (int r = 0; r < 4; ++r)
      hv[r] = (_Float16)(acc[mt][r] * rinv);
    *(half4*)&ctxS[(qs * 16 + c) * 264 + h * D_ + mt * 16 + qd * 4] = hv;
  }
  __syncthreads();

  // ---- epilogue 2: fused output projection (wave w owns 16 n-cols) ----
  const int n0w = w * 16;
  float4v oacc[2] = {zero4, zero4};
#pragma unroll
  for (int ks = 0; ks < 8; ++ks) {
    half8 af0 = *(const half8*)&ctxS[(0 * 16 + c) * 264 + ks * 32 + qd * 8];
    half8 af1 = *(const half8*)&ctxS[(1 * 16 + c) * 264 + ks * 32 + qd * 8];
    half8 bf  = *(const half8*)(WTo + (size_t)(n0w + c) * U_ + ks * 32 + qd * 8);
    oacc[0] = __builtin_amdgcn_mfma_f32_16x16x32_f16(af0, bf, oacc[0], 0, 0, 0);
    oacc[1] = __builtin_amdgcn_mfma_f32_16x16x32_f16(af1, bf, oacc[1], 0, 0, 0);
  }
  const float bias = bo[n0w + c];
#pragma unroll
  for (int mt = 0; mt < 2; ++mt)
#pragma unroll
    for (int r = 0; r < 4; ++r) {
      const int rowl = mt * 16 + qd * 4 + r;
      Out[(size_t)(b * N_ + q0 + rowl) * U_ + n0w + c] = oacc[mt][r] + bias;
    }
}

// ---------------------------------------------------------------------------
extern "C" void kernel_launch(void* const* d_in, const int* in_sizes, int n_in,
                              void* d_out, int out_size, void* d_ws, size_t ws_size,
                              hipStream_t stream) {
  const float* X   = (const float*)d_in[0];
  const int*   Adj = (const int*)d_in[1];
  const float* Wq  = (const float*)d_in[2];
  const float* Wk  = (const float*)d_in[3];
  const float* Wv  = (const float*)d_in[4];
  const float* Wo  = (const float*)d_in[5];
  const float* bo  = (const float*)d_in[6];
  float* Out = (float*)d_out;

  const size_t elems = (size_t)B_ * N_ * U_;   // 4,194,304 halves = 8 MB each
  const size_t wsz   = (size_t)U_ * U_;        // 65,536 halves per weight
  const size_t mask_b = (size_t)B_ * 64 * N_ * sizeof(unsigned);   // 4 MB
  const size_t need_full = (4 * elems + 4 * wsz) * sizeof(_Float16) + mask_b;
  const size_t need_fb   = (3 * elems + 4 * wsz) * sizeof(_Float16) + mask_b;

  if (ws_size >= need_full) {
    _Float16* Xh  = (_Float16*)d_ws;
    _Float16* Qg  = Xh + elems;
    _Float16* Kg  = Qg + elems;
    _Float16* VTg = Kg + elems;
    _Float16* WT  = VTg + elems;
    _Float16* WTq = WT;
    _Float16* WTk = WT + wsz;
    _Float16* WTv = WT + 2 * wsz;
    _Float16* WTo = WT + 3 * wsz;
    unsigned* Maskg = (unsigned*)(WT + 4 * wsz);

    k_prep<<<dim3(64 + 512 + 1024), 256, 0, stream>>>(X, Wq, Wk, Wv, Wo, Adj, Xh, WT, Maskg, 512);
    k_qkv2<<<dim3(6, 256), 256, 0, stream>>>(Xh, WTq, WTk, WTv, Qg, Kg, VTg);
    k_attn<<<dim3(512), 1024, 0, stream>>>(Qg, Kg, VTg, Maskg, WTo, bo, Out);
  } else {
    // Fallback (ws >= 29.9 MB): no Xh; k_qkv converts X in-kernel.
    _Float16* Qg  = (_Float16*)d_ws;
    _Float16* Kg  = Qg + elems;
    _Float16* VTg = Kg + elems;
    _Float16* WT  = VTg + elems;
    _Float16* WTo = WT + 3 * wsz;
    unsigned* Maskg = (unsigned*)(WT + 4 * wsz);

    k_prep<<<dim3(64 + 1024), 256, 0, stream>>>(X, Wq, Wk, Wv, Wo, Adj, Qg /*unused*/, WT, Maskg, 0);
    k_qkv<<<dim3(6, 128), 256, 0, stream>>>(X, Wq, Wk, Wv, Qg, Kg, VTg);
    k_attn<<<dim3(512), 1024, 0, stream>>>(Qg, Kg, VTg, Maskg, WTo, bo, Out);
  }
}

// Round 6
// 379.664 us; speedup vs baseline: 1.0484x; 1.0484x over previous
//
#include <hip/hip_runtime.h>
#include <cstdint>
#include <cstddef>

#define B_ 8
#define N_ 2048
#define H_ 8
#define D_ 32
#define U_ 256

typedef _Float16 half8 __attribute__((ext_vector_type(8)));
typedef _Float16 half4 __attribute__((ext_vector_type(4)));
typedef float float4v __attribute__((ext_vector_type(4)));

__device__ __forceinline__ float fast_exp2(float x) {
#if __has_builtin(__builtin_amdgcn_exp2f)
  return __builtin_amdgcn_exp2f(x);
#else
  return exp2f(x);
#endif
}

// ---------------------------------------------------------------------------
// K0: prep.
//  blocks [0,64):     W transpose -> WT fp16 [n][k], one 64x64 subtile per
//                     block. Wq scaled by log2(e)/sqrt(32).
//  blocks [64,64+nx): X fp32 -> fp16 (nx=512 full path, 0 fallback).
// (Round-5 lesson: the Adj->mask pass cost ~83us and bought 0 in attn —
//  attn is schedule-bound, not memory-bound. Adj ballots stay in k_attn.)
// ---------------------------------------------------------------------------
__global__ __launch_bounds__(256)
void k_prep(const float* __restrict__ X,
            const float* __restrict__ Wq, const float* __restrict__ Wk,
            const float* __restrict__ Wv, const float* __restrict__ Wo,
            _Float16* __restrict__ Xh, _Float16* __restrict__ WT)
{
  __shared__ __attribute__((aligned(16))) float Ts[64][68];
  const int tid = threadIdx.x;
  const int bx = blockIdx.x;
  if (bx < 64) {
    const int wsel = bx >> 4;     // which W
    const int t    = bx & 15;     // which 64x64 subtile
    const float* W = (wsel == 0) ? Wq : (wsel == 1) ? Wk : (wsel == 2) ? Wv : Wo;
    const float scale = (wsel == 0) ? 0.25505413f : 1.0f;
    _Float16* dstW = WT + (size_t)wsel * (U_ * U_);
    const int r = tid >> 2, cs = tid & 3;
    const int k0 = (t >> 2) * 64, n0 = (t & 3) * 64;
#pragma unroll
    for (int j = 0; j < 4; ++j)
      *(float4v*)&Ts[r][cs * 16 + j * 4] =
          *(const float4v*)(W + (size_t)(k0 + r) * U_ + n0 + cs * 16 + j * 4);
    __syncthreads();
#pragma unroll
    for (int j = 0; j < 4; ++j) {
      half4 hv;
#pragma unroll
      for (int jj = 0; jj < 4; ++jj)
        hv[jj] = (_Float16)(Ts[cs * 16 + j * 4 + jj][r] * scale);
      *(half4*)(dstW + (size_t)(n0 + r) * U_ + k0 + cs * 16 + j * 4) = hv;
    }
  } else {
    const size_t base = ((size_t)(bx - 64) * 256 + tid) * 32;
#pragma unroll
    for (int i = 0; i < 4; ++i) {
      float4v a  = *(const float4v*)(X + base + i * 8);
      float4v b2 = *(const float4v*)(X + base + i * 8 + 4);
      half8 hv;
      hv[0] = (_Float16)a[0];  hv[1] = (_Float16)a[1];
      hv[2] = (_Float16)a[2];  hv[3] = (_Float16)a[3];
      hv[4] = (_Float16)b2[0]; hv[5] = (_Float16)b2[1];
      hv[6] = (_Float16)b2[2]; hv[7] = (_Float16)b2[3];
      *(half8*)(Xh + base + i * 8) = hv;
    }
  }
}

// ---------------------------------------------------------------------------
// K1: QKV projection from pre-converted Xh (fp16) and pre-transposed WT.
// 64-row tiles: grid (6,256), LDS 27.6 KB.
// ---------------------------------------------------------------------------
__global__ __launch_bounds__(256, 2)
void k_qkv2(const _Float16* __restrict__ Xh,
            const _Float16* __restrict__ WTq, const _Float16* __restrict__ WTk,
            const _Float16* __restrict__ WTv,
            _Float16* __restrict__ Qg, _Float16* __restrict__ Kg,
            _Float16* __restrict__ VTg)
{
  __shared__ __attribute__((aligned(16))) char qsmem[27648];
  _Float16* Xs = (_Float16*)qsmem;            // [64 m][72]
  _Float16* Ws = (_Float16*)(qsmem + 9216);   // [128 n][72]

  const int tid  = threadIdx.x;
  const int lane = tid & 63;
  const int w    = tid >> 6;
  const int c    = lane & 15;
  const int qd   = lane >> 4;

  const int bx   = blockIdx.x;    // 0..5
  const int proj = bx >> 1;
  const int nh   = bx & 1;
  const int n0l  = nh * 128;
  const int m0   = blockIdx.y * 64;
  const _Float16* WT = (proj == 0) ? WTq : ((proj == 1) ? WTk : WTv);

  const float4v zero4 = {0.f, 0.f, 0.f, 0.f};
  float4v acc[8];
#pragma unroll
  for (int j = 0; j < 8; ++j) acc[j] = zero4;

  const int xrow = tid >> 2, xoff = (tid & 3) * 16;
  const int wrow = tid >> 1, woff = (tid & 1) * 32;
  for (int kt = 0; kt < 4; ++kt) {
    const int k0 = kt * 64;
    {
      const _Float16* src = Xh + (size_t)(m0 + xrow) * U_ + k0 + xoff;
      _Float16* dst = &Xs[xrow * 72 + xoff];
      *(half8*)(dst)     = *(const half8*)(src);
      *(half8*)(dst + 8) = *(const half8*)(src + 8);
    }
    {
      const _Float16* srcw = WT + (size_t)(n0l + wrow) * U_ + k0 + woff;
      _Float16* dstw = &Ws[wrow * 72 + woff];
#pragma unroll
      for (int i = 0; i < 4; ++i)
        *(half8*)(dstw + i * 8) = *(const half8*)(srcw + i * 8);
    }
    __syncthreads();
#pragma unroll
    for (int ks = 0; ks < 2; ++ks) {
      half8 af = *(const half8*)&Xs[(w * 16 + c) * 72 + ks * 32 + qd * 8];
      half8 bf[8];
#pragma unroll
      for (int nt = 0; nt < 8; ++nt)
        bf[nt] = *(const half8*)&Ws[(nt * 16 + c) * 72 + ks * 32 + qd * 8];
#pragma unroll
      for (int nt = 0; nt < 8; ++nt)
        acc[nt] = __builtin_amdgcn_mfma_f32_16x16x32_f16(af, bf[nt], acc[nt], 0, 0, 0);
    }
    __syncthreads();
  }

  const int b   = m0 >> 11;
  const int nb0 = m0 & (N_ - 1);
  if (proj < 2) {
    _Float16* Og = (proj == 0) ? Qg : Kg;
#pragma unroll
    for (int nt = 0; nt < 8; ++nt)
#pragma unroll
      for (int r = 0; r < 4; ++r) {
        const int rowl = w * 16 + qd * 4 + r;
        Og[(size_t)(b * N_ + nb0 + rowl) * U_ + n0l + nt * 16 + c] = (_Float16)acc[nt][r];
      }
  } else {
    _Float16* tr = (_Float16*)qsmem; // [128 u][72 seq]
#pragma unroll
    for (int nt = 0; nt < 8; ++nt)
#pragma unroll
      for (int r = 0; r < 4; ++r)
        tr[(nt * 16 + c) * 72 + w * 16 + qd * 4 + r] = (_Float16)acc[nt][r];
    __syncthreads();
    const int u = tid >> 1;
    const int seg = tid & 1;
    _Float16* dst = VTg + (size_t)(b * U_ + n0l + u) * N_ + nb0 + seg * 32;
#pragma unroll
    for (int i = 0; i < 4; ++i)
      *(half8*)(dst + i * 8) = *(const half8*)&tr[u * 72 + seg * 32 + i * 8];
  }
}

// ---------------------------------------------------------------------------
// K1 (fallback, ws too small): original QKV with in-kernel transpose.
// ---------------------------------------------------------------------------
__global__ __launch_bounds__(256, 2)
void k_qkv(const float* __restrict__ X,
           const float* __restrict__ Wq, const float* __restrict__ Wk,
           const float* __restrict__ Wv,
           _Float16* __restrict__ Qg, _Float16* __restrict__ Kg,
           _Float16* __restrict__ VTg)
{
  __shared__ __attribute__((aligned(16))) char qsmem[36864];
  _Float16* Xs = (_Float16*)qsmem;
  _Float16* Ws = (_Float16*)(qsmem + 18432);

  const int tid  = threadIdx.x;
  const int lane = tid & 63;
  const int w    = tid >> 6;
  const int c    = lane & 15;
  const int qd   = lane >> 4;

  const int bx   = blockIdx.x;
  const int proj = bx >> 1;
  const int nh   = bx & 1;
  const int n0l  = nh * 128;
  const int m0   = blockIdx.y * 128;
  const float* Wp = (proj == 0) ? Wq : ((proj == 1) ? Wk : Wv);
  const float wscale = (proj == 0) ? 0.25505413f : 1.0f;

  const float4v zero4 = {0.f, 0.f, 0.f, 0.f};
  float4v acc[2][8];
#pragma unroll
  for (int i = 0; i < 2; ++i)
#pragma unroll
    for (int j = 0; j < 8; ++j) acc[i][j] = zero4;

  for (int kt = 0; kt < 4; ++kt) {
    const int k0 = kt * 64;
    {
      const int row = tid >> 1;
      const int off = (tid & 1) * 32;
      const float* src = X + (size_t)(m0 + row) * U_ + k0 + off;
      _Float16* dst = &Xs[row * 72 + off];
#pragma unroll
      for (int i = 0; i < 4; ++i) {
        float4v a  = *(const float4v*)(src + i * 8);
        float4v b2 = *(const float4v*)(src + i * 8 + 4);
        half8 hv;
        hv[0] = (_Float16)a[0];  hv[1] = (_Float16)a[1];
        hv[2] = (_Float16)a[2];  hv[3] = (_Float16)a[3];
        hv[4] = (_Float16)b2[0]; hv[5] = (_Float16)b2[1];
        hv[6] = (_Float16)b2[2]; hv[7] = (_Float16)b2[3];
        *(half8*)(dst + i * 8) = hv;
      }
    }
    {
      const int kl = tid & 63;
      const int ng = tid >> 6;
      const float* srcw = Wp + (size_t)(k0 + kl) * U_ + n0l + ng * 32;
#pragma unroll
      for (int j = 0; j < 8; ++j) {
        float4v a = *(const float4v*)(srcw + j * 4);
#pragma unroll
        for (int jj = 0; jj < 4; ++jj)
          Ws[(ng * 32 + j * 4 + jj) * 72 + kl] = (_Float16)(a[jj] * wscale);
      }
    }
    __syncthreads();
#pragma unroll
    for (int ks = 0; ks < 2; ++ks) {
      half8 af[2], bf[8];
#pragma unroll
      for (int mt = 0; mt < 2; ++mt)
        af[mt] = *(const half8*)&Xs[(w * 32 + mt * 16 + c) * 72 + ks * 32 + qd * 8];
#pragma unroll
      for (int nt = 0; nt < 8; ++nt)
        bf[nt] = *(const half8*)&Ws[(nt * 16 + c) * 72 + ks * 32 + qd * 8];
#pragma unroll
      for (int mt = 0; mt < 2; ++mt)
#pragma unroll
        for (int nt = 0; nt < 8; ++nt)
          acc[mt][nt] = __builtin_amdgcn_mfma_f32_16x16x32_f16(af[mt], bf[nt], acc[mt][nt], 0, 0, 0);
    }
    __syncthreads();
  }

  const int b   = m0 >> 11;
  const int nb0 = m0 & (N_ - 1);
  if (proj < 2) {
    _Float16* Og = (proj == 0) ? Qg : Kg;
#pragma unroll
    for (int mt = 0; mt < 2; ++mt)
#pragma unroll
      for (int nt = 0; nt < 8; ++nt)
#pragma unroll
        for (int r = 0; r < 4; ++r) {
          const int rowl = w * 32 + mt * 16 + qd * 4 + r;
          Og[(size_t)(b * N_ + nb0 + rowl) * U_ + n0l + nt * 16 + c] = (_Float16)acc[mt][nt][r];
        }
  } else {
    _Float16* tr = (_Float16*)qsmem;
#pragma unroll
    for (int mt = 0; mt < 2; ++mt)
#pragma unroll
      for (int nt = 0; nt < 8; ++nt)
#pragma unroll
        for (int r = 0; r < 4; ++r)
          tr[(nt * 16 + c) * 136 + w * 32 + mt * 16 + qd * 4 + r] = (_Float16)acc[mt][nt][r];
    __syncthreads();
    const int u = tid >> 1;
    const int seg = tid & 1;
    _Float16* dst = VTg + (size_t)(b * U_ + n0l + u) * N_ + nb0 + seg * 64;
#pragma unroll
    for (int i = 0; i < 8; ++i)
      *(half8*)(dst + i * 8) = *(const half8*)&tr[u * 136 + seg * 64 + i * 8];
  }
}

// ---------------------------------------------------------------------------
// K2: fused masked flash attention + output projection.
// Round 6 = consolidation of proven-best pieces:
//  * R1 attn core: padded LDS (K [32][264], VT [256][40] — 8.45M conflicts,
//    best measured), adj int loads + ballots inside the 2-ahead pipeline.
//  * 512 blocks x 1024 threads (16 waves = 8 heads x 2 q-frags), 32 q-rows.
//  * R5 fused output projection epilogue (no k_out launch, no Cg traffic).
//  * No mask prep pass (R5: cost 83us, saved 0 — attn is schedule-bound).
// ---------------------------------------------------------------------------
#define KS_H (32 * 264)   // halves per K buffer
#define VT_H (256 * 40)   // halves per V^T buffer

struct StageRegs {
  half8 k, v;
  int a;
};

__global__ __launch_bounds__(1024, 4)
void k_attn(const _Float16* __restrict__ Qg, const _Float16* __restrict__ Kg,
            const _Float16* __restrict__ VTg, const int* __restrict__ Adj,
            const _Float16* __restrict__ WTo, const float* __restrict__ bo,
            float* __restrict__ Out)
{
  __shared__ __attribute__((aligned(16))) _Float16 KsB[2][KS_H];   // [32 key][264]
  __shared__ __attribute__((aligned(16))) _Float16 VTsB[2][VT_H];  // [256 u][40]
  __shared__ __attribute__((aligned(8)))  unsigned int maskB[2][32];

  const int tid  = threadIdx.x;
  const int lane = tid & 63;
  const int w    = tid >> 6;   // 0..15
  const int h    = w & 7;      // head
  const int qs   = w >> 3;     // q-frag (0/1), 16 rows each
  const int c    = lane & 15;
  const int qd   = lane >> 4;
  const int wg   = blockIdx.x;
  const int b    = wg & 7;     // XCD-L2 locality
  const int q0   = (wg >> 3) * 32;

  // staging roles (1024 threads)
  const int krow = tid >> 5, kch = tid & 31;   // K: 32 rows x 32 half8-chunks
  const int vu   = tid >> 2, vseg = tid & 3;   // V: 256 rows x 4 half8-chunks
  const _Float16* kptr = Kg + (size_t)(b * N_ + krow) * U_ + kch * 8;
  const _Float16* vptr = VTg + (size_t)(b * U_ + vu) * N_ + vseg * 8;
  const int rr = lane >> 5;
  const int kk = lane & 31;
  const int* aptr = Adj + (size_t)(b * N_ + q0 + w * 2 + rr) * N_ + kk;

  // Q as B-operand frag (pre-scaled by log2(e)/sqrt(d))
  const half8 qb = *(const half8*)(Qg + (size_t)(b * N_ + q0 + qs * 16 + c) * U_ + h * D_ + qd * 8);

  const float4v init4 = {-8.f, -8.f, -8.f, -8.f}; // exp2 bias, cancels in p/l
  const float4v zero4 = {0.f, 0.f, 0.f, 0.f};
  float4v acc[2] = {zero4, zero4};
  float lrow = 0.f;

  auto load_tile = [&](int kt) -> StageRegs {
    StageRegs r;
    r.k = *(const half8*)(kptr + (size_t)kt * 32 * U_);
    r.v = *(const half8*)(vptr + (size_t)kt * 32);
    r.a = aptr[(size_t)kt * 32];
    return r;
  };
  auto store_tile = [&](const StageRegs& r, int buf) {
    *(half8*)&KsB[buf][krow * 264 + kch * 8] = r.k;
    *(half8*)&VTsB[buf][vu * 40 + vseg * 8] = r.v;
    unsigned long long bm = __ballot(r.a > 0);
    if (lane == 0) *(unsigned long long*)&maskB[buf][w * 2] = bm;
  };
  auto compute_tile = [&](int buf) {
    half8 ka0 = *(const half8*)&KsB[buf][(0 * 16 + c) * 264 + h * D_ + qd * 8];
    half8 ka1 = *(const half8*)&KsB[buf][(1 * 16 + c) * 264 + h * D_ + qd * 8];
    half4 va[2][2];
#pragma unroll
    for (int mt = 0; mt < 2; ++mt)
#pragma unroll
      for (int kc = 0; kc < 2; ++kc)
        va[mt][kc] = *(const half4*)&VTsB[buf][(h * D_ + mt * 16 + c) * 40 + kc * 16 + qd * 4];
    float4v s0 = __builtin_amdgcn_mfma_f32_16x16x32_f16(ka0, qb, init4, 0, 0, 0);
    float4v s1 = __builtin_amdgcn_mfma_f32_16x16x32_f16(ka1, qb, init4, 0, 0, 0);
    const unsigned int mq = maskB[buf][qs * 16 + c];
    const unsigned int t0 = mq >> (qd * 4);
    const unsigned int t1 = mq >> (16 + qd * 4);
    half4 pb0, pb1;
    float ls = 0.f;
#pragma unroll
    for (int r = 0; r < 4; ++r) {
      float e0 = fast_exp2(s0[r]);
      float e1 = fast_exp2(s1[r]);
      float p0 = ((t0 >> r) & 1u) ? e0 : 0.f;
      float p1 = ((t1 >> r) & 1u) ? e1 : 0.f;
      ls += p0 + p1;
      pb0[r] = (_Float16)p0;
      pb1[r] = (_Float16)p1;
    }
    lrow += ls;
    acc[0] = __builtin_amdgcn_mfma_f32_16x16x16f16(va[0][0], pb0, acc[0], 0, 0, 0);
    acc[0] = __builtin_amdgcn_mfma_f32_16x16x16f16(va[0][1], pb1, acc[0], 0, 0, 0);
    acc[1] = __builtin_amdgcn_mfma_f32_16x16x16f16(va[1][0], pb0, acc[1], 0, 0, 0);
    acc[1] = __builtin_amdgcn_mfma_f32_16x16x16f16(va[1][1], pb1, acc[1], 0, 0, 0);
  };

  // ---- prologue: tile 0 staged, tile 1 loads in flight ----
  StageRegs rA = load_tile(0);
  store_tile(rA, 0);
  StageRegs rB = load_tile(1);
  __syncthreads();

  // ---- pipelined main loop: loads run 2 tiles ahead of consumption ----
#pragma unroll 1
  for (int kt = 0; kt < 64; kt += 2) {
    if (kt + 2 < 64) rA = load_tile(kt + 2);
    compute_tile(0);                     // tile kt
    store_tile(rB, 1);                   // tile kt+1 (loads covered by compute)
    __syncthreads();
    if (kt + 3 < 64) rB = load_tile(kt + 3);
    compute_tile(1);                     // tile kt+1
    if (kt + 2 < 64) store_tile(rA, 0);  // tile kt+2
    __syncthreads();
  }

  // ---- epilogue 1: reduce l across qd-groups, normalize, ctx -> LDS ----
  float l = lrow;
  l += __shfl_xor(l, 16, 64);
  l += __shfl_xor(l, 32, 64);
  const float rinv = (l > 0.f) ? 1.f / l : 0.f;

  _Float16* ctxS = (_Float16*)KsB;  // reuse K region: [32 q][264]
#pragma unroll
  for (int mt = 0; mt < 2; ++mt) {
    half4 hv;
#pragma unroll
    for (int r = 0; r < 4; ++r)
      hv[r] = (_Float16)(acc[mt][r] * rinv);
    *(half4*)&ctxS[(qs * 16 + c) * 264 + h * D_ + mt * 16 + qd * 4] = hv;
  }
  __syncthreads();

  // ---- epilogue 2: fused output projection (wave w owns 16 n-cols) ----
  const int n0w = w * 16;
  float4v oacc[2] = {zero4, zero4};
#pragma unroll
  for (int ks = 0; ks < 8; ++ks) {
    half8 af0 = *(const half8*)&ctxS[(0 * 16 + c) * 264 + ks * 32 + qd * 8];
    half8 af1 = *(const half8*)&ctxS[(1 * 16 + c) * 264 + ks * 32 + qd * 8];
    half8 bf  = *(const half8*)(WTo + (size_t)(n0w + c) * U_ + ks * 32 + qd * 8);
    oacc[0] = __builtin_amdgcn_mfma_f32_16x16x32_f16(af0, bf, oacc[0], 0, 0, 0);
    oacc[1] = __builtin_amdgcn_mfma_f32_16x16x32_f16(af1, bf, oacc[1], 0, 0, 0);
  }
  const float bias = bo[n0w + c];
#pragma unroll
  for (int mt = 0; mt < 2; ++mt)
#pragma unroll
    for (int r = 0; r < 4; ++r) {
      const int rowl = mt * 16 + qd * 4 + r;
      Out[(size_t)(b * N_ + q0 + rowl) * U_ + n0w + c] = oacc[mt][r] + bias;
    }
}

// ---------------------------------------------------------------------------
extern "C" void kernel_launch(void* const* d_in, const int* in_sizes, int n_in,
                              void* d_out, int out_size, void* d_ws, size_t ws_size,
                              hipStream_t stream) {
  const float* X   = (const float*)d_in[0];
  const int*   Adj = (const int*)d_in[1];
  const float* Wq  = (const float*)d_in[2];
  const float* Wk  = (const float*)d_in[3];
  const float* Wv  = (const float*)d_in[4];
  const float* Wo  = (const float*)d_in[5];
  const float* bo  = (const float*)d_in[6];
  float* Out = (float*)d_out;

  const size_t elems = (size_t)B_ * N_ * U_;   // 4,194,304 halves = 8 MB each
  const size_t wsz   = (size_t)U_ * U_;        // 65,536 halves per weight
  const size_t need_full = (4 * elems + 4 * wsz) * sizeof(_Float16);

  if (ws_size >= need_full) {
    _Float16* Xh  = (_Float16*)d_ws;
    _Float16* Qg  = Xh + elems;
    _Float16* Kg  = Qg + elems;
    _Float16* VTg = Kg + elems;
    _Float16* WT  = VTg + elems;
    _Float16* WTq = WT;
    _Float16* WTk = WT + wsz;
    _Float16* WTv = WT + 2 * wsz;
    _Float16* WTo = WT + 3 * wsz;

    k_prep<<<dim3(64 + 512), 256, 0, stream>>>(X, Wq, Wk, Wv, Wo, Xh, WT);
    k_qkv2<<<dim3(6, 256), 256, 0, stream>>>(Xh, WTq, WTk, WTv, Qg, Kg, VTg);
    k_attn<<<dim3(512), 1024, 0, stream>>>(Qg, Kg, VTg, Adj, WTo, bo, Out);
  } else {
    // Fallback (ws >= 24.5 MB): no Xh; k_qkv converts X in-kernel.
    // k_prep grid=64 produces WT only (Xh blocks not launched).
    _Float16* Qg  = (_Float16*)d_ws;
    _Float16* Kg  = Qg + elems;
    _Float16* VTg = Kg + elems;
    _Float16* WT  = VTg + elems;
    _Float16* WTo = WT + 3 * wsz;

    k_prep<<<dim3(64), 256, 0, stream>>>(X, Wq, Wk, Wv, Wo, Qg /*unused*/, WT);
    k_qkv<<<dim3(6, 128), 256, 0, stream>>>(X, Wq, Wk, Wv, Qg, Kg, VTg);
    k_attn<<<dim3(512), 1024, 0, stream>>>(Qg, Kg, VTg, Adj, WTo, bo, Out);
  }
}

// Round 7
// 303.706 us; speedup vs baseline: 1.3106x; 1.2501x over previous
//
#include <hip/hip_runtime.h>
#include <cstdint>
#include <cstddef>

#define B_ 8
#define N_ 2048
#define H_ 8
#define D_ 32
#define U_ 256

typedef _Float16 half8 __attribute__((ext_vector_type(8)));
typedef _Float16 half4 __attribute__((ext_vector_type(4)));
typedef float float4v __attribute__((ext_vector_type(4)));

__device__ __forceinline__ float fast_exp2(float x) {
#if __has_builtin(__builtin_amdgcn_exp2f)
  return __builtin_amdgcn_exp2f(x);
#else
  return exp2f(x);
#endif
}

// ---------------------------------------------------------------------------
// K0: prep.
//  blocks [0,64):     W transpose -> WT fp16 [n][k], one 64x64 subtile per
//                     block. Wq scaled by log2(e)/sqrt(32).
//  blocks [64,64+nx): X fp32 -> fp16 (nx=512 full path, 0 fallback).
// ---------------------------------------------------------------------------
__global__ __launch_bounds__(256)
void k_prep(const float* __restrict__ X,
            const float* __restrict__ Wq, const float* __restrict__ Wk,
            const float* __restrict__ Wv, const float* __restrict__ Wo,
            _Float16* __restrict__ Xh, _Float16* __restrict__ WT)
{
  __shared__ __attribute__((aligned(16))) float Ts[64][68];
  const int tid = threadIdx.x;
  const int bx = blockIdx.x;
  if (bx < 64) {
    const int wsel = bx >> 4;     // which W
    const int t    = bx & 15;     // which 64x64 subtile
    const float* W = (wsel == 0) ? Wq : (wsel == 1) ? Wk : (wsel == 2) ? Wv : Wo;
    const float scale = (wsel == 0) ? 0.25505413f : 1.0f;
    _Float16* dstW = WT + (size_t)wsel * (U_ * U_);
    const int r = tid >> 2, cs = tid & 3;
    const int k0 = (t >> 2) * 64, n0 = (t & 3) * 64;
#pragma unroll
    for (int j = 0; j < 4; ++j)
      *(float4v*)&Ts[r][cs * 16 + j * 4] =
          *(const float4v*)(W + (size_t)(k0 + r) * U_ + n0 + cs * 16 + j * 4);
    __syncthreads();
#pragma unroll
    for (int j = 0; j < 4; ++j) {
      half4 hv;
#pragma unroll
      for (int jj = 0; jj < 4; ++jj)
        hv[jj] = (_Float16)(Ts[cs * 16 + j * 4 + jj][r] * scale);
      *(half4*)(dstW + (size_t)(n0 + r) * U_ + k0 + cs * 16 + j * 4) = hv;
    }
  } else {
    const size_t base = ((size_t)(bx - 64) * 256 + tid) * 32;
#pragma unroll
    for (int i = 0; i < 4; ++i) {
      float4v a  = *(const float4v*)(X + base + i * 8);
      float4v b2 = *(const float4v*)(X + base + i * 8 + 4);
      half8 hv;
      hv[0] = (_Float16)a[0];  hv[1] = (_Float16)a[1];
      hv[2] = (_Float16)a[2];  hv[3] = (_Float16)a[3];
      hv[4] = (_Float16)b2[0]; hv[5] = (_Float16)b2[1];
      hv[6] = (_Float16)b2[2]; hv[7] = (_Float16)b2[3];
      *(half8*)(Xh + base + i * 8) = hv;
    }
  }
}

// ---------------------------------------------------------------------------
// K1: QKV projection from pre-converted Xh (fp16) and pre-transposed WT.
// 64-row tiles: grid (6,256), LDS 27.6 KB.
// ---------------------------------------------------------------------------
__global__ __launch_bounds__(256, 2)
void k_qkv2(const _Float16* __restrict__ Xh,
            const _Float16* __restrict__ WTq, const _Float16* __restrict__ WTk,
            const _Float16* __restrict__ WTv,
            _Float16* __restrict__ Qg, _Float16* __restrict__ Kg,
            _Float16* __restrict__ VTg)
{
  __shared__ __attribute__((aligned(16))) char qsmem[27648];
  _Float16* Xs = (_Float16*)qsmem;            // [64 m][72]
  _Float16* Ws = (_Float16*)(qsmem + 9216);   // [128 n][72]

  const int tid  = threadIdx.x;
  const int lane = tid & 63;
  const int w    = tid >> 6;
  const int c    = lane & 15;
  const int qd   = lane >> 4;

  const int bx   = blockIdx.x;    // 0..5
  const int proj = bx >> 1;
  const int nh   = bx & 1;
  const int n0l  = nh * 128;
  const int m0   = blockIdx.y * 64;
  const _Float16* WT = (proj == 0) ? WTq : ((proj == 1) ? WTk : WTv);

  const float4v zero4 = {0.f, 0.f, 0.f, 0.f};
  float4v acc[8];
#pragma unroll
  for (int j = 0; j < 8; ++j) acc[j] = zero4;

  const int xrow = tid >> 2, xoff = (tid & 3) * 16;
  const int wrow = tid >> 1, woff = (tid & 1) * 32;
  for (int kt = 0; kt < 4; ++kt) {
    const int k0 = kt * 64;
    {
      const _Float16* src = Xh + (size_t)(m0 + xrow) * U_ + k0 + xoff;
      _Float16* dst = &Xs[xrow * 72 + xoff];
      *(half8*)(dst)     = *(const half8*)(src);
      *(half8*)(dst + 8) = *(const half8*)(src + 8);
    }
    {
      const _Float16* srcw = WT + (size_t)(n0l + wrow) * U_ + k0 + woff;
      _Float16* dstw = &Ws[wrow * 72 + woff];
#pragma unroll
      for (int i = 0; i < 4; ++i)
        *(half8*)(dstw + i * 8) = *(const half8*)(srcw + i * 8);
    }
    __syncthreads();
#pragma unroll
    for (int ks = 0; ks < 2; ++ks) {
      half8 af = *(const half8*)&Xs[(w * 16 + c) * 72 + ks * 32 + qd * 8];
      half8 bf[8];
#pragma unroll
      for (int nt = 0; nt < 8; ++nt)
        bf[nt] = *(const half8*)&Ws[(nt * 16 + c) * 72 + ks * 32 + qd * 8];
#pragma unroll
      for (int nt = 0; nt < 8; ++nt)
        acc[nt] = __builtin_amdgcn_mfma_f32_16x16x32_f16(af, bf[nt], acc[nt], 0, 0, 0);
    }
    __syncthreads();
  }

  const int b   = m0 >> 11;
  const int nb0 = m0 & (N_ - 1);
  if (proj < 2) {
    _Float16* Og = (proj == 0) ? Qg : Kg;
#pragma unroll
    for (int nt = 0; nt < 8; ++nt)
#pragma unroll
      for (int r = 0; r < 4; ++r) {
        const int rowl = w * 16 + qd * 4 + r;
        Og[(size_t)(b * N_ + nb0 + rowl) * U_ + n0l + nt * 16 + c] = (_Float16)acc[nt][r];
      }
  } else {
    _Float16* tr = (_Float16*)qsmem; // [128 u][72 seq]
#pragma unroll
    for (int nt = 0; nt < 8; ++nt)
#pragma unroll
      for (int r = 0; r < 4; ++r)
        tr[(nt * 16 + c) * 72 + w * 16 + qd * 4 + r] = (_Float16)acc[nt][r];
    __syncthreads();
    const int u = tid >> 1;
    const int seg = tid & 1;
    _Float16* dst = VTg + (size_t)(b * U_ + n0l + u) * N_ + nb0 + seg * 32;
#pragma unroll
    for (int i = 0; i < 4; ++i)
      *(half8*)(dst + i * 8) = *(const half8*)&tr[u * 72 + seg * 32 + i * 8];
  }
}

// ---------------------------------------------------------------------------
// K1 (fallback, ws too small): original QKV with in-kernel transpose.
// ---------------------------------------------------------------------------
__global__ __launch_bounds__(256, 2)
void k_qkv(const float* __restrict__ X,
           const float* __restrict__ Wq, const float* __restrict__ Wk,
           const float* __restrict__ Wv,
           _Float16* __restrict__ Qg, _Float16* __restrict__ Kg,
           _Float16* __restrict__ VTg)
{
  __shared__ __attribute__((aligned(16))) char qsmem[36864];
  _Float16* Xs = (_Float16*)qsmem;
  _Float16* Ws = (_Float16*)(qsmem + 18432);

  const int tid  = threadIdx.x;
  const int lane = tid & 63;
  const int w    = tid >> 6;
  const int c    = lane & 15;
  const int qd   = lane >> 4;

  const int bx   = blockIdx.x;
  const int proj = bx >> 1;
  const int nh   = bx & 1;
  const int n0l  = nh * 128;
  const int m0   = blockIdx.y * 128;
  const float* Wp = (proj == 0) ? Wq : ((proj == 1) ? Wk : Wv);
  const float wscale = (proj == 0) ? 0.25505413f : 1.0f;

  const float4v zero4 = {0.f, 0.f, 0.f, 0.f};
  float4v acc[2][8];
#pragma unroll
  for (int i = 0; i < 2; ++i)
#pragma unroll
    for (int j = 0; j < 8; ++j) acc[i][j] = zero4;

  for (int kt = 0; kt < 4; ++kt) {
    const int k0 = kt * 64;
    {
      const int row = tid >> 1;
      const int off = (tid & 1) * 32;
      const float* src = X + (size_t)(m0 + row) * U_ + k0 + off;
      _Float16* dst = &Xs[row * 72 + off];
#pragma unroll
      for (int i = 0; i < 4; ++i) {
        float4v a  = *(const float4v*)(src + i * 8);
        float4v b2 = *(const float4v*)(src + i * 8 + 4);
        half8 hv;
        hv[0] = (_Float16)a[0];  hv[1] = (_Float16)a[1];
        hv[2] = (_Float16)a[2];  hv[3] = (_Float16)a[3];
        hv[4] = (_Float16)b2[0]; hv[5] = (_Float16)b2[1];
        hv[6] = (_Float16)b2[2]; hv[7] = (_Float16)b2[3];
        *(half8*)(dst + i * 8) = hv;
      }
    }
    {
      const int kl = tid & 63;
      const int ng = tid >> 6;
      const float* srcw = Wp + (size_t)(k0 + kl) * U_ + n0l + ng * 32;
#pragma unroll
      for (int j = 0; j < 8; ++j) {
        float4v a = *(const float4v*)(srcw + j * 4);
#pragma unroll
        for (int jj = 0; jj < 4; ++jj)
          Ws[(ng * 32 + j * 4 + jj) * 72 + kl] = (_Float16)(a[jj] * wscale);
      }
    }
    __syncthreads();
#pragma unroll
    for (int ks = 0; ks < 2; ++ks) {
      half8 af[2], bf[8];
#pragma unroll
      for (int mt = 0; mt < 2; ++mt)
        af[mt] = *(const half8*)&Xs[(w * 32 + mt * 16 + c) * 72 + ks * 32 + qd * 8];
#pragma unroll
      for (int nt = 0; nt < 8; ++nt)
        bf[nt] = *(const half8*)&Ws[(nt * 16 + c) * 72 + ks * 32 + qd * 8];
#pragma unroll
      for (int mt = 0; mt < 2; ++mt)
#pragma unroll
        for (int nt = 0; nt < 8; ++nt)
          acc[mt][nt] = __builtin_amdgcn_mfma_f32_16x16x32_f16(af[mt], bf[nt], acc[mt][nt], 0, 0, 0);
    }
    __syncthreads();
  }

  const int b   = m0 >> 11;
  const int nb0 = m0 & (N_ - 1);
  if (proj < 2) {
    _Float16* Og = (proj == 0) ? Qg : Kg;
#pragma unroll
    for (int mt = 0; mt < 2; ++mt)
#pragma unroll
      for (int nt = 0; nt < 8; ++nt)
#pragma unroll
        for (int r = 0; r < 4; ++r) {
          const int rowl = w * 32 + mt * 16 + qd * 4 + r;
          Og[(size_t)(b * N_ + nb0 + rowl) * U_ + n0l + nt * 16 + c] = (_Float16)acc[mt][nt][r];
        }
  } else {
    _Float16* tr = (_Float16*)qsmem;
#pragma unroll
    for (int mt = 0; mt < 2; ++mt)
#pragma unroll
      for (int nt = 0; nt < 8; ++nt)
#pragma unroll
        for (int r = 0; r < 4; ++r)
          tr[(nt * 16 + c) * 136 + w * 32 + mt * 16 + qd * 4 + r] = (_Float16)acc[mt][nt][r];
    __syncthreads();
    const int u = tid >> 1;
    const int seg = tid & 1;
    _Float16* dst = VTg + (size_t)(b * U_ + n0l + u) * N_ + nb0 + seg * 64;
#pragma unroll
    for (int i = 0; i < 8; ++i)
      *(half8*)(dst + i * 8) = *(const half8*)&tr[u * 136 + seg * 64 + i * 8];
  }
}

// ---------------------------------------------------------------------------
// K2: fused masked flash attention + output projection.
// Round 7 = Round-1 attn core VERBATIM (proven 125.6us):
//   256 blocks x 1024 threads, 64 q-rows/block (wave = head x 32-row q-half,
//   qb[2]/acc[2][2]), padded LDS K [32][264] + VT [256][40], 2 ballots/wave
//   covering 4 adj rows, pipelined 2-tiles-ahead, 1 barrier/tile.
// + fused output projection epilogue (R5/R6-proven: ~2us in-kernel, deletes
//   the ~25us k_out launch + Cg round-trip). ctx [64][264] exactly fills the
//   two K LDS buffers.
// (R6 lesson: 32 q-rows/block doubled staging:compute ratio -> 191us. 64 is
//  the amortization optimum at 1 block/CU.)
// ---------------------------------------------------------------------------
#define KS_H (32 * 264)   // halves per K buffer
#define VT_H (256 * 40)   // halves per V^T buffer

struct StageRegs {
  half8 k0, v0;
  int a0, a1;
};

__global__ __launch_bounds__(1024, 4)
void k_attn(const _Float16* __restrict__ Qg, const _Float16* __restrict__ Kg,
            const _Float16* __restrict__ VTg, const int* __restrict__ Adj,
            const _Float16* __restrict__ WTo, const float* __restrict__ bo,
            float* __restrict__ Out)
{
  __shared__ __attribute__((aligned(16))) _Float16 KsB[2][KS_H];   // [32 key][264]
  __shared__ __attribute__((aligned(16))) _Float16 VTsB[2][VT_H];  // [256 u][40]
  __shared__ __attribute__((aligned(8)))  unsigned int maskB[2][64];

  const int tid  = threadIdx.x;
  const int lane = tid & 63;
  const int w    = tid >> 6;   // 0..15
  const int h    = w & 7;      // head
  const int qh   = w >> 3;     // q-half (0/1), 32 rows each
  const int c    = lane & 15;
  const int qd   = lane >> 4;
  const int wg   = blockIdx.x;
  const int b    = wg & 7;     // XCD-L2 locality
  const int q0   = (wg >> 3) * 64;

  const _Float16* kptr = Kg + (size_t)(b * N_ + (tid >> 5)) * U_ + (tid & 31) * 8;
  const _Float16* vptr = VTg + (size_t)(b * U_ + (tid >> 2)) * N_ + (tid & 3) * 8;
  const int rr = lane >> 5;
  const int kk = lane & 31;
  const int* aptr = Adj + (size_t)(b * N_ + q0 + w * 4 + rr) * N_ + kk;

  // Q as B-operand frags (pre-scaled by log2(e)/sqrt(d))
  half8 qb[2];
#pragma unroll
  for (int nt = 0; nt < 2; ++nt)
    qb[nt] = *(const half8*)(Qg + (size_t)(b * N_ + q0 + qh * 32 + nt * 16 + c) * U_ + h * D_ + qd * 8);

  const float4v init4 = {-8.f, -8.f, -8.f, -8.f}; // exp2 bias, cancels in p/l
  const float4v zero4 = {0.f, 0.f, 0.f, 0.f};
  float4v acc[2][2];
#pragma unroll
  for (int i = 0; i < 2; ++i)
#pragma unroll
    for (int j = 0; j < 2; ++j) acc[i][j] = zero4;
  float lrow[2] = {0.f, 0.f};

  auto load_tile = [&](int kt) -> StageRegs {
    StageRegs r;
    r.k0 = *(const half8*)(kptr + (size_t)kt * 32 * U_);
    r.v0 = *(const half8*)(vptr + (size_t)kt * 32);
    const int* as = aptr + (size_t)kt * 32;
    r.a0 = as[0];
    r.a1 = as[2 * N_];
    return r;
  };
  auto store_tile = [&](const StageRegs& r, int buf) {
    *(half8*)&KsB[buf][(tid >> 5) * 264 + (tid & 31) * 8] = r.k0;
    *(half8*)&VTsB[buf][(tid >> 2) * 40 + (tid & 3) * 8] = r.v0;
    unsigned long long bm;
    bm = __ballot(r.a0 > 0); if (lane == 0) *(unsigned long long*)&maskB[buf][w * 4 + 0] = bm;
    bm = __ballot(r.a1 > 0); if (lane == 0) *(unsigned long long*)&maskB[buf][w * 4 + 2] = bm;
  };
  auto compute_tile = [&](int buf) {
    half8 ka0 = *(const half8*)&KsB[buf][(0 * 16 + c) * 264 + h * D_ + qd * 8];
    half8 ka1 = *(const half8*)&KsB[buf][(1 * 16 + c) * 264 + h * D_ + qd * 8];
    half4 va[2][2];
#pragma unroll
    for (int mt = 0; mt < 2; ++mt)
#pragma unroll
      for (int kc = 0; kc < 2; ++kc)
        va[mt][kc] = *(const half4*)&VTsB[buf][(h * D_ + mt * 16 + c) * 40 + kc * 16 + qd * 4];
#pragma unroll
    for (int nt = 0; nt < 2; ++nt) {
      float4v s0 = __builtin_amdgcn_mfma_f32_16x16x32_f16(ka0, qb[nt], init4, 0, 0, 0);
      float4v s1 = __builtin_amdgcn_mfma_f32_16x16x32_f16(ka1, qb[nt], init4, 0, 0, 0);
      const unsigned int mq = maskB[buf][qh * 32 + nt * 16 + c];
      const unsigned int t0 = mq >> (qd * 4);
      const unsigned int t1 = mq >> (16 + qd * 4);
      half4 pb0, pb1;
      float ls = 0.f;
#pragma unroll
      for (int r = 0; r < 4; ++r) {
        float e0 = fast_exp2(s0[r]);
        float e1 = fast_exp2(s1[r]);
        float p0 = ((t0 >> r) & 1u) ? e0 : 0.f;
        float p1 = ((t1 >> r) & 1u) ? e1 : 0.f;
        ls += p0 + p1;
        pb0[r] = (_Float16)p0;
        pb1[r] = (_Float16)p1;
      }
      lrow[nt] += ls;
      acc[0][nt] = __builtin_amdgcn_mfma_f32_16x16x16f16(va[0][0], pb0, acc[0][nt], 0, 0, 0);
      acc[0][nt] = __builtin_amdgcn_mfma_f32_16x16x16f16(va[0][1], pb1, acc[0][nt], 0, 0, 0);
      acc[1][nt] = __builtin_amdgcn_mfma_f32_16x16x16f16(va[1][0], pb0, acc[1][nt], 0, 0, 0);
      acc[1][nt] = __builtin_amdgcn_mfma_f32_16x16x16f16(va[1][1], pb1, acc[1][nt], 0, 0, 0);
    }
  };

  // ---- prologue: tile 0 staged, tile 1 loads in flight ----
  StageRegs rA = load_tile(0);
  store_tile(rA, 0);
  StageRegs rB = load_tile(1);
  __syncthreads();

  // ---- pipelined main loop: loads run 2 tiles ahead of consumption ----
#pragma unroll 1
  for (int kt = 0; kt < 64; kt += 2) {
    if (kt + 2 < 64) rA = load_tile(kt + 2);
    compute_tile(0);                     // tile kt
    store_tile(rB, 1);                   // tile kt+1 (loads covered by compute)
    __syncthreads();
    if (kt + 3 < 64) rB = load_tile(kt + 3);
    compute_tile(1);                     // tile kt+1
    if (kt + 2 < 64) store_tile(rA, 0);  // tile kt+2
    __syncthreads();
  }

  // ---- epilogue 1: reduce l across qd-groups, normalize, ctx -> LDS ----
  float rinv[2];
#pragma unroll
  for (int nt = 0; nt < 2; ++nt) {
    float l = lrow[nt];
    l += __shfl_xor(l, 16, 64);
    l += __shfl_xor(l, 32, 64);
    rinv[nt] = (l > 0.f) ? 1.f / l : 0.f;
  }
  _Float16* ctxS = (_Float16*)KsB;  // reuse both K buffers: [64 q][264]
#pragma unroll
  for (int mt = 0; mt < 2; ++mt)
#pragma unroll
    for (int nt = 0; nt < 2; ++nt) {
      half4 hv;
#pragma unroll
      for (int r = 0; r < 4; ++r)
        hv[r] = (_Float16)(acc[mt][nt][r] * rinv[nt]);
      *(half4*)&ctxS[(qh * 32 + nt * 16 + c) * 264 + h * D_ + mt * 16 + qd * 4] = hv;
    }
  __syncthreads();

  // ---- epilogue 2: fused output projection (wave w owns 16 n-cols, 64 rows)
  const int n0w = w * 16;
  float4v oacc[4] = {zero4, zero4, zero4, zero4};
#pragma unroll
  for (int ks = 0; ks < 8; ++ks) {
    half8 bf = *(const half8*)(WTo + (size_t)(n0w + c) * U_ + ks * 32 + qd * 8);
#pragma unroll
    for (int mt = 0; mt < 4; ++mt) {
      half8 af = *(const half8*)&ctxS[(mt * 16 + c) * 264 + ks * 32 + qd * 8];
      oacc[mt] = __builtin_amdgcn_mfma_f32_16x16x32_f16(af, bf, oacc[mt], 0, 0, 0);
    }
  }
  const float bias = bo[n0w + c];
#pragma unroll
  for (int mt = 0; mt < 4; ++mt)
#pragma unroll
    for (int r = 0; r < 4; ++r) {
      const int rowl = mt * 16 + qd * 4 + r;
      Out[(size_t)(b * N_ + q0 + rowl) * U_ + n0w + c] = oacc[mt][r] + bias;
    }
}

// ---------------------------------------------------------------------------
extern "C" void kernel_launch(void* const* d_in, const int* in_sizes, int n_in,
                              void* d_out, int out_size, void* d_ws, size_t ws_size,
                              hipStream_t stream) {
  const float* X   = (const float*)d_in[0];
  const int*   Adj = (const int*)d_in[1];
  const float* Wq  = (const float*)d_in[2];
  const float* Wk  = (const float*)d_in[3];
  const float* Wv  = (const float*)d_in[4];
  const float* Wo  = (const float*)d_in[5];
  const float* bo  = (const float*)d_in[6];
  float* Out = (float*)d_out;

  const size_t elems = (size_t)B_ * N_ * U_;   // 4,194,304 halves = 8 MB each
  const size_t wsz   = (size_t)U_ * U_;        // 65,536 halves per weight
  const size_t need_full = (4 * elems + 4 * wsz) * sizeof(_Float16);

  if (ws_size >= need_full) {
    _Float16* Xh  = (_Float16*)d_ws;
    _Float16* Qg  = Xh + elems;
    _Float16* Kg  = Qg + elems;
    _Float16* VTg = Kg + elems;
    _Float16* WT  = VTg + elems;
    _Float16* WTq = WT;
    _Float16* WTk = WT + wsz;
    _Float16* WTv = WT + 2 * wsz;
    _Float16* WTo = WT + 3 * wsz;

    k_prep<<<dim3(64 + 512), 256, 0, stream>>>(X, Wq, Wk, Wv, Wo, Xh, WT);
    k_qkv2<<<dim3(6, 256), 256, 0, stream>>>(Xh, WTq, WTk, WTv, Qg, Kg, VTg);
    k_attn<<<dim3(256), 1024, 0, stream>>>(Qg, Kg, VTg, Adj, WTo, bo, Out);
  } else {
    // Fallback (ws >= 24.5 MB): no Xh; k_qkv converts X in-kernel.
    _Float16* Qg  = (_Float16*)d_ws;
    _Float16* Kg  = Qg + elems;
    _Float16* VTg = Kg + elems;
    _Float16* WT  = VTg + elems;
    _Float16* WTo = WT + 3 * wsz;

    k_prep<<<dim3(64), 256, 0, stream>>>(X, Wq, Wk, Wv, Wo, Qg /*unused*/, WT);
    k_qkv<<<dim3(6, 128), 256, 0, stream>>>(X, Wq, Wk, Wv, Qg, Kg, VTg);
    k_attn<<<dim3(256), 1024, 0, stream>>>(Qg, Kg, VTg, Adj, WTo, bo, Out);
  }
}